// Round 19
// baseline (44.118 us; speedup 1.0000x reference)
//
#include <hip/hip_runtime.h>
#include <stdint.h>

#define NB 4
#define NT 2048
#define NC 1024
#define NH 64
#define NM (NB*NT)

typedef unsigned short u16;
typedef unsigned int u32;
typedef __bf16 bf16_t;
typedef float f32x4 __attribute__((ext_vector_type(4)));
typedef bf16_t bf16x8 __attribute__((ext_vector_type(8)));
typedef u16 u16x8 __attribute__((ext_vector_type(8)));
typedef u16 u16x4 __attribute__((ext_vector_type(4)));

__device__ __forceinline__ u16 f2b(float f) {
  return __builtin_bit_cast(u16, (bf16_t)f);
}
__device__ __forceinline__ float b2f(u16 u) {
  return (float)__builtin_bit_cast(bf16_t, u);
}

// async global->LDS 16B: LDS dest = WAVE-UNIFORM base + lane*16 (m104);
// per-lane swizzle folded into the GLOBAL source address (m173).
__device__ __forceinline__ void gl16(const void* g, void* l) {
  __builtin_amdgcn_global_load_lds(
      (const __attribute__((address_space(1))) u32*)g,
      (__attribute__((address_space(3))) u32*)l, 16, 0, 0);
}

// ---------------- Wq/Wk/Wv [1024][64] f32 -> WT [3][64][1024] bf16 (r13 layout)
__global__ __launch_bounds__(256) void wt_kernel(const float* __restrict__ Wq,
                                                 const float* __restrict__ Wk,
                                                 const float* __restrict__ Wv,
                                                 u16* __restrict__ wt) {
  __shared__ float t[64][65];
  const int m = blockIdx.x >> 4;
  const int kt = blockIdx.x & 15;
  const int k0 = kt * 64;
  const float* W = (m == 0) ? Wq : (m == 1) ? Wk : Wv;
  {
    const int r = threadIdx.x >> 2, c4 = threadIdx.x & 3;
    #pragma unroll
    for (int j = 0; j < 4; ++j) {
      const float4 f = *(const float4*)(W + (size_t)(k0 + r) * NH + c4 * 16 + j * 4);
      t[r][c4 * 16 + j * 4 + 0] = f.x;
      t[r][c4 * 16 + j * 4 + 1] = f.y;
      t[r][c4 * 16 + j * 4 + 2] = f.z;
      t[r][c4 * 16 + j * 4 + 3] = f.w;
    }
  }
  __syncthreads();
  const int n = threadIdx.x >> 2, kc = threadIdx.x & 3;
  u16x8 a, b;
  #pragma unroll
  for (int j = 0; j < 8; ++j) a[j] = f2b(t[kc * 16 + j][n]);
  #pragma unroll
  for (int j = 0; j < 8; ++j) b[j] = f2b(t[kc * 16 + 8 + j][n]);
  u16* dst = wt + ((size_t)(m * 64 + n)) * NC + k0 + kc * 16;
  *(u16x8*)dst = a;
  *(u16x8*)(dst + 8) = b;
}

// ---------------- proj-v6: K-split-4 x BM=64 -> 512 blocks (2/CU, one round).
// Per block: 2 halves x { single-shot stage A(32KB f32)+B(48KB bf16) via gl16,
// ONE vmcnt(0)+barrier, 4 MFMA K-steps }. bf16 partials pc[split][8192][192].
// Traffic: 81MB staged (vs 196-295 in r13/r15) and 2 barrier-drains (vs 16).
__global__ __launch_bounds__(256) void proj_kernel(const float* __restrict__ x,
                                                   const u16* __restrict__ wt,
                                                   u16* __restrict__ pc) {
  __shared__ float sA[64 * 128];    // 32 KB, [row][k] 16B-chunk XOR swizzle
  __shared__ u16 sB[192 * 128];     // 48 KB, [n][k] same swizzle
  const int tid = threadIdx.x;
  const int lane = tid & 63;
  const int cg = tid >> 6;          // col group 0..3 (48 cols each)
  const int g = lane >> 4;
  const int li = lane & 15;
  const int msel = blockIdx.x >> 2;
  const int split = blockIdx.x & 3;
  const int row0 = msel * 64;
  const int wbase = tid & 0xC0;

  const f32x4 zero = {0.f, 0.f, 0.f, 0.f};
  f32x4 acc[4][3];
  #pragma unroll
  for (int rt = 0; rt < 4; ++rt)
    #pragma unroll
    for (int f = 0; f < 3; ++f) acc[rt][f] = zero;

  auto stage = [&](int h) {
    const int kf = split * 256 + h * 128;   // f32/u16 k-base
    #pragma unroll
    for (int j = 0; j < 8; ++j) {           // A: 64 rows x 32 chunks
      const int slot = j * 256 + tid;
      const int r = slot >> 5, c = slot & 31;
      gl16(x + (size_t)(row0 + r) * NC + kf + ((c ^ (r & 7)) * 4),
           (char*)sA + (j * 256 + wbase) * 16);
    }
    #pragma unroll
    for (int j = 0; j < 12; ++j) {          // B: 192 rows x 16 chunks
      const int slot = j * 256 + tid;
      const int n = slot >> 4, c = slot & 15;
      gl16(wt + (size_t)n * NC + kf + ((c ^ (n & 7)) * 8),
           (char*)sB + (j * 256 + wbase) * 16);
    }
  };

  #pragma unroll
  for (int h = 0; h < 2; ++h) {
    stage(h);
    asm volatile("s_waitcnt vmcnt(0)" ::: "memory");
    __syncthreads();
    #pragma unroll
    for (int s = 0; s < 4; ++s) {
      bf16x8 aF[4];
      #pragma unroll
      for (int rt = 0; rt < 4; ++rt) {
        const int r = rt * 16 + li;
        const int c0 = s * 8 + g * 2;
        const f32x4 a0 = *(const f32x4*)&sA[r * 128 + ((c0 ^ (r & 7)) * 4)];
        const f32x4 a1 = *(const f32x4*)&sA[r * 128 + (((c0 + 1) ^ (r & 7)) * 4)];
        bf16x8 v;
        v[0]=(bf16_t)a0.x; v[1]=(bf16_t)a0.y; v[2]=(bf16_t)a0.z; v[3]=(bf16_t)a0.w;
        v[4]=(bf16_t)a1.x; v[5]=(bf16_t)a1.y; v[6]=(bf16_t)a1.z; v[7]=(bf16_t)a1.w;
        aF[rt] = v;
      }
      #pragma unroll
      for (int f = 0; f < 3; ++f) {
        const int n = (cg * 3 + f) * 16 + li;
        const bf16x8 bF = *(const bf16x8*)&sB[n * 128 + (((s * 4 + g) ^ (n & 7)) * 8)];
        #pragma unroll
        for (int rt = 0; rt < 4; ++rt)
          acc[rt][f] = __builtin_amdgcn_mfma_f32_16x16x32_bf16(aF[rt], bF, acc[rt][f], 0, 0, 0);
      }
    }
    if (h == 0) __syncthreads();   // all reads done before re-staging
  }

  // epilogue: partials, C/D layout col=lane&15, row=(lane>>4)*4+reg
  #pragma unroll
  for (int rt = 0; rt < 4; ++rt) {
    const int rr0 = row0 + rt * 16 + g * 4;
    #pragma unroll
    for (int f = 0; f < 3; ++f) {
      const int col = (cg * 3 + f) * 16 + li;
      #pragma unroll
      for (int i = 0; i < 4; ++i)
        pc[((size_t)split * NM + rr0 + i) * 192 + col] = f2b(acc[rt][f][i]);
    }
  }
}

// ---------------- merge 4 K-splits -> qb / kb / vtb (existing layouts)
__global__ __launch_bounds__(256) void pmerge_kernel(const u16* __restrict__ pc,
                                                     u16* __restrict__ qo,
                                                     u16* __restrict__ ko,
                                                     u16* __restrict__ vto) {
  const int gid = blockIdx.x * 256 + threadIdx.x;   // 0 .. 8192*48-1
  const int row = gid / 48;
  const int c0 = (gid % 48) * 4;
  float s0 = 0.f, s1 = 0.f, s2 = 0.f, s3 = 0.f;
  #pragma unroll
  for (int s = 0; s < 4; ++s) {
    const u16x4 v = *(const u16x4*)&pc[((size_t)s * NM + row) * 192 + c0];
    s0 += b2f(v[0]); s1 += b2f(v[1]); s2 += b2f(v[2]); s3 += b2f(v[3]);
  }
  u16x4 o;
  o[0] = f2b(s0); o[1] = f2b(s1); o[2] = f2b(s2); o[3] = f2b(s3);
  if (c0 < 64) {
    *(u16x4*)&qo[(size_t)row * NH + c0] = o;
  } else if (c0 < 128) {
    *(u16x4*)&ko[(size_t)row * NH + (c0 - 64)] = o;
  } else {
    const int hs0 = c0 - 128;
    const int bidx = row >> 11;
    const int tt = row & 2047;
    const int tile = tt >> 6, off = tt & 63;
    #pragma unroll
    for (int i = 0; i < 4; ++i)
      vto[(((size_t)(bidx * 32 + tile) * 64) + hs0 + i) * 64 + off] = o[i];
  }
}

// ---------------- attention (r18 — byte-identical)
struct AttnGrp {
  union {
    u16 K[2][32 * 64];                                    // 8 KB
    struct { float mo[2][16][64]; float ml[2][16]; } mg;  // merge alias
  } u;
};

__global__ __launch_bounds__(512) void attn_kernel(const u16* __restrict__ qg,
                                                   const u16* __restrict__ kg,
                                                   const u16* __restrict__ vtg,
                                                   float* __restrict__ out) {
  __shared__ AttnGrp grp[8];
  __shared__ u16 sP[8][16 * 32];
  const int tid = threadIdx.x;
  const int lane = tid & 63;
  const int s = tid >> 6;
  const int g = lane >> 4;
  const int li = lane & 15;
  const int jA = blockIdx.x & 63;
  const int bb = blockIdx.x >> 6;
  const int jB = 127 - jA;
  const size_t bt0 = (size_t)bb * NT;
  const int q0A = jA * 16, q0B = jB * 16;
  const int n1 = (jA >> 1) + 1;
  const int nB = 64 - (jA >> 1);

  bf16x8 aqA[2], aqB[2];
  #pragma unroll
  for (int ks = 0; ks < 2; ++ks) {
    aqA[ks] = *(const bf16x8*)(qg + (bt0 + q0A + li) * NH + ks * 32 + g * 8);
    aqB[ks] = *(const bf16x8*)(qg + (bt0 + q0B + li) * NH + ks * 32 + g * 8);
  }

  const f32x4 zero = {0.f, 0.f, 0.f, 0.f};
  f32x4 oA[4], oB[4];
  float lA[4], lB[4];
  #pragma unroll
  for (int i = 0; i < 4; ++i) { oA[i] = zero; oB[i] = zero; lA[i] = 0.f; lB[i] = 0.f; }

  auto stageK = [&](int t, int b) {
    const size_t kbase = bt0 + (size_t)t * 32;
    #pragma unroll
    for (int jj = 0; jj < 4; ++jj) {
      const int idx = jj * 64 + lane;
      const int n = idx >> 3, c = idx & 7;
      gl16(kg + (kbase + n) * NH + ((c ^ (n & 7)) * 8),
           (char*)grp[s].u.K[b] + jj * 1024);
    }
  };

  auto computeT = [&](const bf16x8 (&aq)[2], f32x4 (&o)[4], float (&ls)[4],
                      int q0, int kv0, int b, const bf16x8 (&vf)[4]) {
    f32x4 sc2[2] = {zero, zero};
    #pragma unroll
    for (int ks = 0; ks < 2; ++ks) {
      #pragma unroll
      for (int fn = 0; fn < 2; ++fn) {
        const int n = fn * 16 + li;
        const bf16x8 bk = *(const bf16x8*)&grp[s].u.K[b][n * 64 + (((ks * 4 + g) ^ (n & 7)) * 8)];
        sc2[fn] = __builtin_amdgcn_mfma_f32_16x16x32_bf16(aq[ks], bk, sc2[fn], 0, 0, 0);
      }
    }
    const bool needmask = (kv0 + 31 > q0);
    #pragma unroll
    for (int fn = 0; fn < 2; ++fn) {
      #pragma unroll
      for (int i = 0; i < 4; ++i) {
        const int q = g * 4 + i;
        float v = sc2[fn][i] * 0.125f;
        if (needmask && (kv0 + fn * 16 + li > q0 + q)) v = -1e30f;
        const float e = __expf(v);
        ls[i] += e;
        const int kc = fn * 2 + (li >> 3);
        sP[s][q * 32 + ((kc ^ (q & 3) ^ ((q >> 2) & 3)) * 8) + (li & 7)] = f2b(e);
      }
    }
    const bf16x8 pa = *(const bf16x8*)&sP[s][li * 32 + ((g ^ (li & 3) ^ ((li >> 2) & 3)) * 8)];
    #pragma unroll
    for (int fn = 0; fn < 4; ++fn)
      o[fn] = __builtin_amdgcn_mfma_f32_16x16x32_bf16(pa, vf[fn], o[fn], 0, 0, 0);
  };

  stageK(s, 0);
  int k = 0;
  for (int t = s; t < nB; t += 8, ++k) {
    bf16x8 vf[4];
    const size_t vrow = ((size_t)(bb * 32 + (t >> 1))) * 64;
    const int hoff = (t & 1) * 32;
    #pragma unroll
    for (int fn = 0; fn < 4; ++fn)
      vf[fn] = *(const bf16x8*)(vtg + (vrow + fn * 16 + li) * 64 + hoff + g * 8);

    if (t + 8 < nB) {
      stageK(t + 8, (k + 1) & 1);
      asm volatile("s_waitcnt vmcnt(8)" ::: "memory");
    } else {
      asm volatile("s_waitcnt vmcnt(4)" ::: "memory");
    }
    const int b = k & 1;
    computeT(aqB, oB, lB, q0B, t * 32, b, vf);
    if (t < n1) computeT(aqA, oA, lA, q0A, t * 32, b, vf);
  }

  #pragma unroll
  for (int i = 0; i < 4; ++i) {
    float a = lA[i], c = lB[i];
    a += __shfl_xor(a, 1); c += __shfl_xor(c, 1);
    a += __shfl_xor(a, 2); c += __shfl_xor(c, 2);
    a += __shfl_xor(a, 4); c += __shfl_xor(c, 4);
    a += __shfl_xor(a, 8); c += __shfl_xor(c, 8);
    lA[i] = a; lB[i] = c;
  }

  #pragma unroll
  for (int fn = 0; fn < 4; ++fn) {
    #pragma unroll
    for (int i = 0; i < 4; ++i) {
      grp[s].u.mg.mo[0][g * 4 + i][fn * 16 + li] = oA[fn][i];
      grp[s].u.mg.mo[1][g * 4 + i][fn * 16 + li] = oB[fn][i];
    }
  }
  if (li == 0) {
    #pragma unroll
    for (int i = 0; i < 4; ++i) {
      grp[s].u.mg.ml[0][g * 4 + i] = lA[i];
      grp[s].u.mg.ml[1][g * 4 + i] = lB[i];
    }
  }
  __syncthreads();

  {
    const int base = tid * 4;
    const int tile = base >> 10;
    const int r = (base >> 6) & 15;
    const int c0 = base & 63;
    float L = 0.f;
    f32x4 acc = zero;
    #pragma unroll
    for (int s8 = 0; s8 < 8; ++s8) {
      L += grp[s8].u.mg.ml[tile][r];
      acc += *(const f32x4*)&grp[s8].u.mg.mo[tile][r][c0];
    }
    const int row = (tile ? q0B : q0A) + r;
    const float inv = 1.f / L;
    acc *= inv;
    *(f32x4*)&out[(bt0 + row) * NH + c0] = acc;
  }
}

extern "C" void kernel_launch(void* const* d_in, const int* in_sizes, int n_in,
                              void* d_out, int out_size, void* d_ws, size_t ws_size,
                              hipStream_t stream) {
  (void)in_sizes; (void)n_in; (void)out_size; (void)ws_size;
  const float* x  = (const float*)d_in[0];
  const float* Wq = (const float*)d_in[1];
  const float* Wk = (const float*)d_in[2];
  const float* Wv = (const float*)d_in[3];
  float* out = (float*)d_out;
  char* ws = (char*)d_ws;
  u16* qb  = (u16*)(ws);                                // 1 MB    : q bf16 [8192][64]
  u16* kb  = (u16*)(ws + (1u << 20));                   // 1 MB    : k bf16 [8192][64]
  u16* vtb = (u16*)(ws + (2u << 20));                   // 1 MB    : v^T tiled [4][32][64][64]
  u16* wtb = (u16*)(ws + (3u << 20));                   // 384 KB  : WT bf16 [3][64][1024]
  u16* pcb = (u16*)(ws + (3u << 20) + (512u << 10));    // 12.6 MB : partials [4][8192][192]
  hipLaunchKernelGGL(wt_kernel,     dim3(48),   dim3(256), 0, stream, Wq, Wk, Wv, wtb);
  hipLaunchKernelGGL(proj_kernel,   dim3(512),  dim3(256), 0, stream, x, wtb, pcb);
  hipLaunchKernelGGL(pmerge_kernel, dim3(1536), dim3(256), 0, stream, pcb, qb, kb, vtb);
  hipLaunchKernelGGL(attn_kernel,   dim3(256),  dim3(512), 0, stream, qb, kb, vtb, out);
}

// Round 20
// 43.411 us; speedup vs baseline: 1.0163x; 1.0163x over previous
//
#include <hip/hip_runtime.h>
#include <stdint.h>

#define NB 4
#define NT 2048
#define NC 1024
#define NH 64
#define NM (NB*NT)

typedef unsigned short u16;
typedef unsigned int u32;
typedef __bf16 bf16_t;
typedef float f32x4 __attribute__((ext_vector_type(4)));
typedef bf16_t bf16x8 __attribute__((ext_vector_type(8)));
typedef u16 u16x8 __attribute__((ext_vector_type(8)));
typedef u16 u16x4 __attribute__((ext_vector_type(4)));

__device__ __forceinline__ u16 f2b(float f) {
  return __builtin_bit_cast(u16, (bf16_t)f);
}
__device__ __forceinline__ float b2f(u16 u) {
  return (float)__builtin_bit_cast(bf16_t, u);
}

// async global->LDS 16B: LDS dest = WAVE-UNIFORM base + lane*16 (m104);
// per-lane swizzle folded into the GLOBAL source address (m173).
__device__ __forceinline__ void gl16(const void* g, void* l) {
  __builtin_amdgcn_global_load_lds(
      (const __attribute__((address_space(1))) u32*)g,
      (__attribute__((address_space(3))) u32*)l, 16, 0, 0);
}

// ---------------- Wq/Wk/Wv [1024][64] f32 -> WT [3][64][1024] bf16 (r13 layout)
__global__ __launch_bounds__(256) void wt_kernel(const float* __restrict__ Wq,
                                                 const float* __restrict__ Wk,
                                                 const float* __restrict__ Wv,
                                                 u16* __restrict__ wt) {
  __shared__ float t[64][65];
  const int m = blockIdx.x >> 4;
  const int kt = blockIdx.x & 15;
  const int k0 = kt * 64;
  const float* W = (m == 0) ? Wq : (m == 1) ? Wk : Wv;
  {
    const int r = threadIdx.x >> 2, c4 = threadIdx.x & 3;
    #pragma unroll
    for (int j = 0; j < 4; ++j) {
      const float4 f = *(const float4*)(W + (size_t)(k0 + r) * NH + c4 * 16 + j * 4);
      t[r][c4 * 16 + j * 4 + 0] = f.x;
      t[r][c4 * 16 + j * 4 + 1] = f.y;
      t[r][c4 * 16 + j * 4 + 2] = f.z;
      t[r][c4 * 16 + j * 4 + 3] = f.w;
    }
  }
  __syncthreads();
  const int n = threadIdx.x >> 2, kc = threadIdx.x & 3;
  u16x8 a, b;
  #pragma unroll
  for (int j = 0; j < 8; ++j) a[j] = f2b(t[kc * 16 + j][n]);
  #pragma unroll
  for (int j = 0; j < 8; ++j) b[j] = f2b(t[kc * 16 + 8 + j][n]);
  u16* dst = wt + ((size_t)(m * 64 + n)) * NC + k0 + kc * 16;
  *(u16x8*)dst = a;
  *(u16x8*)(dst + 8) = b;
}

// ---------------- proj-v7: B-panel K-slice resident in LDS (staged ONCE), A-tiles
// streamed through a double buffer with stage(t+1) || compute(t) overlap (r13
// structure). K-split KSPL across blockIdx.y; 64 M-groups x 128 rows.
// KLEN=128: LDS 64KB -> 2 blocks/CU, staged total 57MB. KLEN=256: fallback.
template<int KLEN>
__global__ __launch_bounds__(256) void proj_kernel(const float* __restrict__ x,
                                                   const u16* __restrict__ wt,
                                                   u16* __restrict__ pc) {
  constexpr int BCH = KLEN / 8;           // u16x8 chunks per B row
  constexpr int ACH = KLEN / 4;           // f32x4 chunks per A row
  constexpr int NBJ = 192 * BCH / 256;    // B gl16 per thread (12 / 24)
  constexpr int NAJ = (16 * ACH) / 256;   // A gl16 per thread per tile (2 / 4)
  __shared__ u16 sB[192 * KLEN];
  __shared__ float sA[2][16 * KLEN];
  const int tid = threadIdx.x;
  const int lane = tid & 63;
  const int cg = tid >> 6;                // col group 0..3 (48 cols each)
  const int g = lane >> 4;
  const int li = lane & 15;
  const int row0 = blockIdx.x * 128;
  const int split = blockIdx.y;
  const int kbase = split * KLEN;
  const int wbase = tid & 0xC0;

  const f32x4 zero = {0.f, 0.f, 0.f, 0.f};

  auto stageB = [&]() {
    #pragma unroll
    for (int j = 0; j < NBJ; ++j) {
      const int slot = j * 256 + tid;
      const int n = slot / BCH, c = slot % BCH;
      gl16(wt + (size_t)n * NC + kbase + ((c ^ (n & 7)) * 8),
           (char*)sB + (j * 256 + wbase) * 16);
    }
  };
  auto stageA = [&](int t, int buf) {
    const int r0 = row0 + t * 16;
    #pragma unroll
    for (int j = 0; j < NAJ; ++j) {
      const int slot = j * 256 + tid;
      const int r = slot / ACH, c = slot % ACH;
      gl16(x + (size_t)(r0 + r) * NC + kbase + ((c ^ (r & 7)) * 4),
           (char*)sA[buf] + (j * 256 + wbase) * 16);
    }
  };

  stageB();
  stageA(0, 0);
  __syncthreads();

  for (int t = 0; t < 8; ++t) {
    const int cur = t & 1;
    if (t < 7) stageA(t + 1, cur ^ 1);
    f32x4 acc[3];
    #pragma unroll
    for (int f = 0; f < 3; ++f) acc[f] = zero;
    #pragma unroll
    for (int s = 0; s < KLEN / 32; ++s) {
      const int r = li;
      const int c0 = s * 8 + g * 2;
      const f32x4 a0 = *(const f32x4*)&sA[cur][r * KLEN + ((c0 ^ (r & 7)) * 4)];
      const f32x4 a1 = *(const f32x4*)&sA[cur][r * KLEN + (((c0 + 1) ^ (r & 7)) * 4)];
      bf16x8 a;
      a[0]=(bf16_t)a0.x; a[1]=(bf16_t)a0.y; a[2]=(bf16_t)a0.z; a[3]=(bf16_t)a0.w;
      a[4]=(bf16_t)a1.x; a[5]=(bf16_t)a1.y; a[6]=(bf16_t)a1.z; a[7]=(bf16_t)a1.w;
      #pragma unroll
      for (int f = 0; f < 3; ++f) {
        const int n = (cg * 3 + f) * 16 + li;
        const bf16x8 bF = *(const bf16x8*)&sB[n * KLEN + (((s * 4 + g) ^ (n & 7)) * 8)];
        acc[f] = __builtin_amdgcn_mfma_f32_16x16x32_bf16(a, bF, acc[f], 0, 0, 0);
      }
    }
    // write this tile's partials: C/D layout col=lane&15, row=(lane>>4)*4+reg
    const int rr0 = row0 + t * 16 + g * 4;
    #pragma unroll
    for (int f = 0; f < 3; ++f) {
      const int col = (cg * 3 + f) * 16 + li;
      #pragma unroll
      for (int i = 0; i < 4; ++i)
        pc[((size_t)split * NM + rr0 + i) * 192 + col] = f2b(acc[f][i]);
    }
    __syncthreads();
  }
}

// ---------------- merge KSPL K-splits -> qb / kb / vtb (existing layouts)
template<int KSPL>
__global__ __launch_bounds__(256) void pmerge_kernel(const u16* __restrict__ pc,
                                                     u16* __restrict__ qo,
                                                     u16* __restrict__ ko,
                                                     u16* __restrict__ vto) {
  const int gid = blockIdx.x * 256 + threadIdx.x;   // 0 .. 8192*48-1
  const int row = gid / 48;
  const int c0 = (gid % 48) * 4;
  float s0 = 0.f, s1 = 0.f, s2 = 0.f, s3 = 0.f;
  #pragma unroll
  for (int s = 0; s < KSPL; ++s) {
    const u16x4 v = *(const u16x4*)&pc[((size_t)s * NM + row) * 192 + c0];
    s0 += b2f(v[0]); s1 += b2f(v[1]); s2 += b2f(v[2]); s3 += b2f(v[3]);
  }
  u16x4 o;
  o[0] = f2b(s0); o[1] = f2b(s1); o[2] = f2b(s2); o[3] = f2b(s3);
  if (c0 < 64) {
    *(u16x4*)&qo[(size_t)row * NH + c0] = o;
  } else if (c0 < 128) {
    *(u16x4*)&ko[(size_t)row * NH + (c0 - 64)] = o;
  } else {
    const int hs0 = c0 - 128;
    const int bidx = row >> 11;
    const int tt = row & 2047;
    const int tile = tt >> 6, off = tt & 63;
    #pragma unroll
    for (int i = 0; i < 4; ++i)
      vto[(((size_t)(bidx * 32 + tile) * 64) + hs0 + i) * 64 + off] = o[i];
  }
}

// ---------------- attention (r18 — byte-identical)
struct AttnGrp {
  union {
    u16 K[2][32 * 64];                                    // 8 KB
    struct { float mo[2][16][64]; float ml[2][16]; } mg;  // merge alias
  } u;
};

__global__ __launch_bounds__(512) void attn_kernel(const u16* __restrict__ qg,
                                                   const u16* __restrict__ kg,
                                                   const u16* __restrict__ vtg,
                                                   float* __restrict__ out) {
  __shared__ AttnGrp grp[8];
  __shared__ u16 sP[8][16 * 32];
  const int tid = threadIdx.x;
  const int lane = tid & 63;
  const int s = tid >> 6;
  const int g = lane >> 4;
  const int li = lane & 15;
  const int jA = blockIdx.x & 63;
  const int bb = blockIdx.x >> 6;
  const int jB = 127 - jA;
  const size_t bt0 = (size_t)bb * NT;
  const int q0A = jA * 16, q0B = jB * 16;
  const int n1 = (jA >> 1) + 1;
  const int nB = 64 - (jA >> 1);

  bf16x8 aqA[2], aqB[2];
  #pragma unroll
  for (int ks = 0; ks < 2; ++ks) {
    aqA[ks] = *(const bf16x8*)(qg + (bt0 + q0A + li) * NH + ks * 32 + g * 8);
    aqB[ks] = *(const bf16x8*)(qg + (bt0 + q0B + li) * NH + ks * 32 + g * 8);
  }

  const f32x4 zero = {0.f, 0.f, 0.f, 0.f};
  f32x4 oA[4], oB[4];
  float lA[4], lB[4];
  #pragma unroll
  for (int i = 0; i < 4; ++i) { oA[i] = zero; oB[i] = zero; lA[i] = 0.f; lB[i] = 0.f; }

  auto stageK = [&](int t, int b) {
    const size_t kbase = bt0 + (size_t)t * 32;
    #pragma unroll
    for (int jj = 0; jj < 4; ++jj) {
      const int idx = jj * 64 + lane;
      const int n = idx >> 3, c = idx & 7;
      gl16(kg + (kbase + n) * NH + ((c ^ (n & 7)) * 8),
           (char*)grp[s].u.K[b] + jj * 1024);
    }
  };

  auto computeT = [&](const bf16x8 (&aq)[2], f32x4 (&o)[4], float (&ls)[4],
                      int q0, int kv0, int b, const bf16x8 (&vf)[4]) {
    f32x4 sc2[2] = {zero, zero};
    #pragma unroll
    for (int ks = 0; ks < 2; ++ks) {
      #pragma unroll
      for (int fn = 0; fn < 2; ++fn) {
        const int n = fn * 16 + li;
        const bf16x8 bk = *(const bf16x8*)&grp[s].u.K[b][n * 64 + (((ks * 4 + g) ^ (n & 7)) * 8)];
        sc2[fn] = __builtin_amdgcn_mfma_f32_16x16x32_bf16(aq[ks], bk, sc2[fn], 0, 0, 0);
      }
    }
    const bool needmask = (kv0 + 31 > q0);
    #pragma unroll
    for (int fn = 0; fn < 2; ++fn) {
      #pragma unroll
      for (int i = 0; i < 4; ++i) {
        const int q = g * 4 + i;
        float v = sc2[fn][i] * 0.125f;
        if (needmask && (kv0 + fn * 16 + li > q0 + q)) v = -1e30f;
        const float e = __expf(v);
        ls[i] += e;
        const int kc = fn * 2 + (li >> 3);
        sP[s][q * 32 + ((kc ^ (q & 3) ^ ((q >> 2) & 3)) * 8) + (li & 7)] = f2b(e);
      }
    }
    const bf16x8 pa = *(const bf16x8*)&sP[s][li * 32 + ((g ^ (li & 3) ^ ((li >> 2) & 3)) * 8)];
    #pragma unroll
    for (int fn = 0; fn < 4; ++fn)
      o[fn] = __builtin_amdgcn_mfma_f32_16x16x32_bf16(pa, vf[fn], o[fn], 0, 0, 0);
  };

  stageK(s, 0);
  int k = 0;
  for (int t = s; t < nB; t += 8, ++k) {
    bf16x8 vf[4];
    const size_t vrow = ((size_t)(bb * 32 + (t >> 1))) * 64;
    const int hoff = (t & 1) * 32;
    #pragma unroll
    for (int fn = 0; fn < 4; ++fn)
      vf[fn] = *(const bf16x8*)(vtg + (vrow + fn * 16 + li) * 64 + hoff + g * 8);

    if (t + 8 < nB) {
      stageK(t + 8, (k + 1) & 1);
      asm volatile("s_waitcnt vmcnt(8)" ::: "memory");
    } else {
      asm volatile("s_waitcnt vmcnt(4)" ::: "memory");
    }
    const int b = k & 1;
    computeT(aqB, oB, lB, q0B, t * 32, b, vf);
    if (t < n1) computeT(aqA, oA, lA, q0A, t * 32, b, vf);
  }

  #pragma unroll
  for (int i = 0; i < 4; ++i) {
    float a = lA[i], c = lB[i];
    a += __shfl_xor(a, 1); c += __shfl_xor(c, 1);
    a += __shfl_xor(a, 2); c += __shfl_xor(c, 2);
    a += __shfl_xor(a, 4); c += __shfl_xor(c, 4);
    a += __shfl_xor(a, 8); c += __shfl_xor(c, 8);
    lA[i] = a; lB[i] = c;
  }

  #pragma unroll
  for (int fn = 0; fn < 4; ++fn) {
    #pragma unroll
    for (int i = 0; i < 4; ++i) {
      grp[s].u.mg.mo[0][g * 4 + i][fn * 16 + li] = oA[fn][i];
      grp[s].u.mg.mo[1][g * 4 + i][fn * 16 + li] = oB[fn][i];
    }
  }
  if (li == 0) {
    #pragma unroll
    for (int i = 0; i < 4; ++i) {
      grp[s].u.mg.ml[0][g * 4 + i] = lA[i];
      grp[s].u.mg.ml[1][g * 4 + i] = lB[i];
    }
  }
  __syncthreads();

  {
    const int base = tid * 4;
    const int tile = base >> 10;
    const int r = (base >> 6) & 15;
    const int c0 = base & 63;
    float L = 0.f;
    f32x4 acc = zero;
    #pragma unroll
    for (int s8 = 0; s8 < 8; ++s8) {
      L += grp[s8].u.mg.ml[tile][r];
      acc += *(const f32x4*)&grp[s8].u.mg.mo[tile][r][c0];
    }
    const int row = (tile ? q0B : q0A) + r;
    const float inv = 1.f / L;
    acc *= inv;
    *(f32x4*)&out[(bt0 + row) * NH + c0] = acc;
  }
}

extern "C" void kernel_launch(void* const* d_in, const int* in_sizes, int n_in,
                              void* d_out, int out_size, void* d_ws, size_t ws_size,
                              hipStream_t stream) {
  (void)in_sizes; (void)n_in; (void)out_size;
  const float* x  = (const float*)d_in[0];
  const float* Wq = (const float*)d_in[1];
  const float* Wk = (const float*)d_in[2];
  const float* Wv = (const float*)d_in[3];
  float* out = (float*)d_out;
  char* ws = (char*)d_ws;
  u16* qb  = (u16*)(ws);                                // 1 MB    : q bf16 [8192][64]
  u16* kb  = (u16*)(ws + (1u << 20));                   // 1 MB    : k bf16 [8192][64]
  u16* vtb = (u16*)(ws + (2u << 20));                   // 1 MB    : v^T tiled [4][32][64][64]
  u16* wtb = (u16*)(ws + (3u << 20));                   // 384 KB  : WT bf16 [3][64][1024]
  u16* pcb = (u16*)(ws + (3u << 20) + (512u << 10));    // partials [KSPL][8192][192] bf16

  hipLaunchKernelGGL(wt_kernel, dim3(48), dim3(256), 0, stream, Wq, Wk, Wv, wtb);
  const size_t need8 = (3u << 20) + (512u << 10) + (size_t)8 * NM * 192 * 2;  // ~28.8 MB
  if (ws_size >= need8) {
    hipLaunchKernelGGL((proj_kernel<128>),  dim3(64, 8), dim3(256), 0, stream, x, wtb, pcb);
    hipLaunchKernelGGL((pmerge_kernel<8>),  dim3(1536),  dim3(256), 0, stream, pcb, qb, kb, vtb);
  } else {
    hipLaunchKernelGGL((proj_kernel<256>),  dim3(64, 4), dim3(256), 0, stream, x, wtb, pcb);
    hipLaunchKernelGGL((pmerge_kernel<4>),  dim3(1536),  dim3(256), 0, stream, pcb, qb, kb, vtb);
  }
  hipLaunchKernelGGL(attn_kernel, dim3(256), dim3(512), 0, stream, qb, kb, vtb, out);
}

// Round 21
// 40.626 us; speedup vs baseline: 1.0860x; 1.0686x over previous
//
#include <hip/hip_runtime.h>
#include <stdint.h>

#define NB 4
#define NT 2048
#define NC 1024
#define NH 64
#define NM (NB*NT)

typedef unsigned short u16;
typedef unsigned int u32;
typedef __bf16 bf16_t;
typedef float f32x4 __attribute__((ext_vector_type(4)));
typedef bf16_t bf16x8 __attribute__((ext_vector_type(8)));
typedef u16 u16x8 __attribute__((ext_vector_type(8)));
typedef u16 u16x4 __attribute__((ext_vector_type(4)));

__device__ __forceinline__ u16 f2b(float f) {
  return __builtin_bit_cast(u16, (bf16_t)f);
}

// async global->LDS 16B: LDS dest = WAVE-UNIFORM base + lane*16 (m104);
// per-lane swizzle folded into the GLOBAL source address (m173).
__device__ __forceinline__ void gl16(const void* g, void* l) {
  __builtin_amdgcn_global_load_lds(
      (const __attribute__((address_space(1))) u32*)g,
      (__attribute__((address_space(3))) u32*)l, 16, 0, 0);
}

// ---------------- Wq/Wk/Wv [1024][64] f32 -> WT [3][64][1024] bf16 (r13 layout)
__global__ __launch_bounds__(256) void wt_kernel(const float* __restrict__ Wq,
                                                 const float* __restrict__ Wk,
                                                 const float* __restrict__ Wv,
                                                 u16* __restrict__ wt) {
  __shared__ float t[64][65];
  const int m = blockIdx.x >> 4;
  const int kt = blockIdx.x & 15;
  const int k0 = kt * 64;
  const float* W = (m == 0) ? Wq : (m == 1) ? Wk : Wv;
  {
    const int r = threadIdx.x >> 2, c4 = threadIdx.x & 3;
    #pragma unroll
    for (int j = 0; j < 4; ++j) {
      const float4 f = *(const float4*)(W + (size_t)(k0 + r) * NH + c4 * 16 + j * 4);
      t[r][c4 * 16 + j * 4 + 0] = f.x;
      t[r][c4 * 16 + j * 4 + 1] = f.y;
      t[r][c4 * 16 + j * 4 + 2] = f.z;
      t[r][c4 * 16 + j * 4 + 3] = f.w;
    }
  }
  __syncthreads();
  const int n = threadIdx.x >> 2, kc = threadIdx.x & 3;
  u16x8 a, b;
  #pragma unroll
  for (int j = 0; j < 8; ++j) a[j] = f2b(t[kc * 16 + j][n]);
  #pragma unroll
  for (int j = 0; j < 8; ++j) b[j] = f2b(t[kc * 16 + 8 + j][n]);
  u16* dst = wt + ((size_t)(m * 64 + n)) * NC + k0 + kc * 16;
  *(u16x8*)dst = a;
  *(u16x8*)(dst + 8) = b;
}

// ---------------- proj-v8: BM=32, K-step=32, one matrix per block-column.
// grid (256,3) x 256 thr; LDS 16KB -> ~6 blocks/CU (the high-delivery regime,
// per the r13/r15/r10 delivery-vs-occupancy law) with r13's stage||compute||barrier
// structure. Traffic 196MB (vs r15's 295MB) in the same regime. No partials.
__global__ __launch_bounds__(256, 4) void proj_kernel(const float* __restrict__ x,
                                                      const u16* __restrict__ wt,
                                                      u16* __restrict__ qo,
                                                      u16* __restrict__ ko,
                                                      u16* __restrict__ vto) {
  __shared__ float fA[2][32 * 32];   // 4KB each: [row][k] 16B-chunk XOR swizzle (8 chunks)
  __shared__ u16 sB2[2][64 * 32];    // 4KB each: [n][k] 16B-chunk XOR swizzle (4 chunks)
  const int tid = threadIdx.x;
  const int lane = tid & 63;
  const int w = tid >> 6;            // wave = 16-col fragment 0..3
  const int g = lane >> 4;
  const int li = lane & 15;
  const int row0 = blockIdx.x * 32;
  const int m = blockIdx.y;          // 0=q 1=k 2=v
  const int wbase = tid & 0xC0;
  const u16* wslice = wt + (size_t)m * 64 * NC;

  const f32x4 zero = {0.f, 0.f, 0.f, 0.f};
  f32x4 acc[2];
  acc[0] = zero; acc[1] = zero;

  // staging coords (1 gl16 each for A and B per thread per step)
  const int arow = tid >> 3, ach = tid & 7;       // A: 32 rows x 8 chunks
  const int brow = tid >> 2, bch = tid & 3;       // B: 64 rows x 4 chunks
  const float* asrc = x + (size_t)(row0 + arow) * NC + ((ach ^ (arow & 7)) * 4);
  const u16* bsrc = wslice + (size_t)brow * NC + ((bch ^ (brow & 3)) * 8);

  auto stage = [&](int kt, int buf) {
    const int k0 = kt * 32;
    gl16(asrc + k0, (char*)fA[buf] + wbase * 16);
    gl16(bsrc + k0, (char*)sB2[buf] + wbase * 16);
  };

  stage(0, 0);
  __syncthreads();

  for (int kt = 0; kt < 32; ++kt) {
    const int cur = kt & 1;
    if (kt < 31) stage(kt + 1, cur ^ 1);
    // A fragments for both row-subtiles (k=32 -> one bf16x8 per subtile)
    bf16x8 aF[2];
    #pragma unroll
    for (int rt = 0; rt < 2; ++rt) {
      const int r = rt * 16 + li;
      const f32x4 a0 = *(const f32x4*)&fA[cur][r * 32 + (((2 * g) ^ (r & 7)) * 4)];
      const f32x4 a1 = *(const f32x4*)&fA[cur][r * 32 + (((2 * g + 1) ^ (r & 7)) * 4)];
      bf16x8 v;
      v[0]=(bf16_t)a0.x; v[1]=(bf16_t)a0.y; v[2]=(bf16_t)a0.z; v[3]=(bf16_t)a0.w;
      v[4]=(bf16_t)a1.x; v[5]=(bf16_t)a1.y; v[6]=(bf16_t)a1.z; v[7]=(bf16_t)a1.w;
      aF[rt] = v;
    }
    const int n = w * 16 + li;
    const bf16x8 bF = *(const bf16x8*)&sB2[cur][n * 32 + ((g ^ (n & 3)) * 8)];
    acc[0] = __builtin_amdgcn_mfma_f32_16x16x32_bf16(aF[0], bF, acc[0], 0, 0, 0);
    acc[1] = __builtin_amdgcn_mfma_f32_16x16x32_bf16(aF[1], bF, acc[1], 0, 0, 0);
    __syncthreads();
  }

  // epilogue: C/D layout col=lane&15, row=(lane>>4)*4+reg; vto tile-blocked
  #pragma unroll
  for (int rt = 0; rt < 2; ++rt) {
    const int rr0 = row0 + rt * 16 + g * 4;
    if (m == 0) {
      #pragma unroll
      for (int i = 0; i < 4; ++i)
        qo[(size_t)(rr0 + i) * NH + w * 16 + li] = f2b(acc[rt][i]);
    } else if (m == 1) {
      #pragma unroll
      for (int i = 0; i < 4; ++i)
        ko[(size_t)(rr0 + i) * NH + w * 16 + li] = f2b(acc[rt][i]);
    } else {
      u16x4 pv;
      #pragma unroll
      for (int i = 0; i < 4; ++i) pv[i] = f2b(acc[rt][i]);
      const int hs = w * 16 + li;
      const int bidx = rr0 >> 11;
      const int tt = rr0 & 2047;
      const int tile = tt >> 6, off = tt & 63;
      *(u16x4*)&vto[(((size_t)(bidx * 32 + tile) * 64) + hs) * 64 + off] = pv;
    }
  }
}

// ---------------- attention (r13 — byte-identical; the r15-best config's attn)
struct AttnGrp {
  union {
    struct { u16 K[2][32 * 64]; u16 V[2][64 * 32]; } st;  // 16 KB
    struct { float mo[2][16][64]; float ml[2][16]; } mg;  // merge alias
  } u;
};

__global__ __launch_bounds__(512) void attn_kernel(const u16* __restrict__ qg,
                                                   const u16* __restrict__ kg,
                                                   const u16* __restrict__ vtg,
                                                   float* __restrict__ out) {
  __shared__ AttnGrp grp[8];
  __shared__ u16 sP[8][16 * 32];
  const int tid = threadIdx.x;
  const int lane = tid & 63;
  const int s = tid >> 6;
  const int g = lane >> 4;
  const int li = lane & 15;
  const int jA = blockIdx.x & 63;
  const int bb = blockIdx.x >> 6;
  const int jB = 127 - jA;
  const size_t bt0 = (size_t)bb * NT;
  const int q0A = jA * 16, q0B = jB * 16;
  const int n1 = (jA >> 1) + 1;
  const int nB = 64 - (jA >> 1);

  bf16x8 aqA[2], aqB[2];
  #pragma unroll
  for (int ks = 0; ks < 2; ++ks) {
    aqA[ks] = *(const bf16x8*)(qg + (bt0 + q0A + li) * NH + ks * 32 + g * 8);
    aqB[ks] = *(const bf16x8*)(qg + (bt0 + q0B + li) * NH + ks * 32 + g * 8);
  }

  const f32x4 zero = {0.f, 0.f, 0.f, 0.f};
  f32x4 oA[4], oB[4];
  float lA[4], lB[4];
  #pragma unroll
  for (int i = 0; i < 4; ++i) { oA[i] = zero; oB[i] = zero; lA[i] = 0.f; lB[i] = 0.f; }

  auto stageKV = [&](int v, int b) {
    const int kvt = (v < n1) ? v : v - n1;
    const size_t kbase = bt0 + (size_t)kvt * 32;
    #pragma unroll
    for (int jj = 0; jj < 4; ++jj) {
      const int idx = jj * 64 + lane;
      const int n = idx >> 3, c = idx & 7;
      gl16(kg + (kbase + n) * NH + ((c ^ (n & 7)) * 8),
           (char*)grp[s].u.st.K[b] + jj * 1024);
    }
    const size_t vbase = ((size_t)(bb * 32 + (kvt >> 1))) * 64;
    const int hoff = (kvt & 1) * 32;
    #pragma unroll
    for (int jj = 0; jj < 4; ++jj) {
      const int idx = jj * 64 + lane;
      const int n = idx >> 2, c = idx & 3;
      gl16(vtg + (vbase + n) * 64 + hoff + ((c ^ (n & 3) ^ ((n >> 2) & 3)) * 8),
           (char*)grp[s].u.st.V[b] + jj * 1024);
    }
  };

  auto computeT = [&](const bf16x8 (&aq)[2], f32x4 (&o)[4], float (&ls)[4],
                      int q0, int kv0, int b) {
    f32x4 sc2[2] = {zero, zero};
    #pragma unroll
    for (int ks = 0; ks < 2; ++ks) {
      #pragma unroll
      for (int fn = 0; fn < 2; ++fn) {
        const int n = fn * 16 + li;
        const bf16x8 bk = *(const bf16x8*)&grp[s].u.st.K[b][n * 64 + (((ks * 4 + g) ^ (n & 7)) * 8)];
        sc2[fn] = __builtin_amdgcn_mfma_f32_16x16x32_bf16(aq[ks], bk, sc2[fn], 0, 0, 0);
      }
    }
    const bool needmask = (kv0 + 31 > q0);
    #pragma unroll
    for (int fn = 0; fn < 2; ++fn) {
      #pragma unroll
      for (int i = 0; i < 4; ++i) {
        const int q = g * 4 + i;
        float v = sc2[fn][i] * 0.125f;
        if (needmask && (kv0 + fn * 16 + li > q0 + q)) v = -1e30f;
        const float e = __expf(v);
        ls[i] += e;
        const int kc = fn * 2 + (li >> 3);
        sP[s][q * 32 + ((kc ^ (q & 3) ^ ((q >> 2) & 3)) * 8) + (li & 7)] = f2b(e);
      }
    }
    const bf16x8 pa = *(const bf16x8*)&sP[s][li * 32 + ((g ^ (li & 3) ^ ((li >> 2) & 3)) * 8)];
    #pragma unroll
    for (int fn = 0; fn < 4; ++fn) {
      const int n = fn * 16 + li;
      const bf16x8 bv = *(const bf16x8*)&grp[s].u.st.V[b][n * 32 + ((g ^ (n & 3) ^ ((n >> 2) & 3)) * 8)];
      o[fn] = __builtin_amdgcn_mfma_f32_16x16x32_bf16(pa, bv, o[fn], 0, 0, 0);
    }
  };

  const int nt = (64 - s) / 8 + 1;
  int v = s;
  stageKV(v, 0);
  for (int k = 0; k < nt; ++k) {
    if (k + 1 < nt) {
      stageKV(v + 8, (k + 1) & 1);
      asm volatile("s_waitcnt vmcnt(8)" ::: "memory");
    } else {
      asm volatile("s_waitcnt vmcnt(0)" ::: "memory");
    }
    const int b = k & 1;
    if (v < n1) computeT(aqA, oA, lA, q0A, v * 32, b);
    else        computeT(aqB, oB, lB, q0B, (v - n1) * 32, b);
    v += 8;
  }

  #pragma unroll
  for (int i = 0; i < 4; ++i) {
    float a = lA[i], c = lB[i];
    a += __shfl_xor(a, 1); c += __shfl_xor(c, 1);
    a += __shfl_xor(a, 2); c += __shfl_xor(c, 2);
    a += __shfl_xor(a, 4); c += __shfl_xor(c, 4);
    a += __shfl_xor(a, 8); c += __shfl_xor(c, 8);
    lA[i] = a; lB[i] = c;
  }

  #pragma unroll
  for (int fn = 0; fn < 4; ++fn) {
    #pragma unroll
    for (int i = 0; i < 4; ++i) {
      grp[s].u.mg.mo[0][g * 4 + i][fn * 16 + li] = oA[fn][i];
      grp[s].u.mg.mo[1][g * 4 + i][fn * 16 + li] = oB[fn][i];
    }
  }
  if (li == 0) {
    #pragma unroll
    for (int i = 0; i < 4; ++i) {
      grp[s].u.mg.ml[0][g * 4 + i] = lA[i];
      grp[s].u.mg.ml[1][g * 4 + i] = lB[i];
    }
  }
  __syncthreads();

  {
    const int base = tid * 4;
    const int tile = base >> 10;
    const int r = (base >> 6) & 15;
    const int c0 = base & 63;
    float L = 0.f;
    f32x4 acc = zero;
    #pragma unroll
    for (int s8 = 0; s8 < 8; ++s8) {
      L += grp[s8].u.mg.ml[tile][r];
      acc += *(const f32x4*)&grp[s8].u.mg.mo[tile][r][c0];
    }
    const int row = (tile ? q0B : q0A) + r;
    const float inv = 1.f / L;
    acc *= inv;
    *(f32x4*)&out[(bt0 + row) * NH + c0] = acc;
  }
}

extern "C" void kernel_launch(void* const* d_in, const int* in_sizes, int n_in,
                              void* d_out, int out_size, void* d_ws, size_t ws_size,
                              hipStream_t stream) {
  (void)in_sizes; (void)n_in; (void)out_size; (void)ws_size;
  const float* x  = (const float*)d_in[0];
  const float* Wq = (const float*)d_in[1];
  const float* Wk = (const float*)d_in[2];
  const float* Wv = (const float*)d_in[3];
  float* out = (float*)d_out;
  char* ws = (char*)d_ws;
  u16* qb  = (u16*)(ws);                    // 1 MB   : q bf16 [8192][64]
  u16* kb  = (u16*)(ws + (1u << 20));       // 1 MB   : k bf16 [8192][64]
  u16* vtb = (u16*)(ws + (2u << 20));       // 1 MB   : v^T bf16 tiled [4][32][64][64]
  u16* wtb = (u16*)(ws + (3u << 20));       // 384 KB : WT bf16 [3][64][1024]
  hipLaunchKernelGGL(wt_kernel,   dim3(48),     dim3(256), 0, stream, Wq, Wk, Wv, wtb);
  hipLaunchKernelGGL(proj_kernel, dim3(256, 3), dim3(256), 0, stream, x, wtb, qb, kb, vtb);
  hipLaunchKernelGGL(attn_kernel, dim3(256),    dim3(512), 0, stream, qb, kb, vtb, out);
}

// Round 22
// 37.919 us; speedup vs baseline: 1.1635x; 1.0714x over previous
//
#include <hip/hip_runtime.h>
#include <stdint.h>

#define NB 4
#define NT 2048
#define NC 1024
#define NH 64
#define NM (NB*NT)

typedef unsigned short u16;
typedef unsigned int u32;
typedef __bf16 bf16_t;
typedef float f32x4 __attribute__((ext_vector_type(4)));
typedef bf16_t bf16x8 __attribute__((ext_vector_type(8)));
typedef u16 u16x8 __attribute__((ext_vector_type(8)));
typedef u16 u16x4 __attribute__((ext_vector_type(4)));

__device__ __forceinline__ u16 f2b(float f) {
  return __builtin_bit_cast(u16, (bf16_t)f);
}

// async global->LDS 16B: LDS dest = WAVE-UNIFORM base + lane*16 (m104);
// per-lane swizzle folded into the GLOBAL source address (m173).
__device__ __forceinline__ void gl16(const void* g, void* l) {
  __builtin_amdgcn_global_load_lds(
      (const __attribute__((address_space(1))) u32*)g,
      (__attribute__((address_space(3))) u32*)l, 16, 0, 0);
}

// ---------------- Wq/Wk/Wv [1024][64] f32 -> WT [3][64][1024] bf16 (transposed)
__global__ __launch_bounds__(256) void wt_kernel(const float* __restrict__ Wq,
                                                 const float* __restrict__ Wk,
                                                 const float* __restrict__ Wv,
                                                 u16* __restrict__ wt) {
  __shared__ float t[64][65];
  const int m = blockIdx.x >> 4;
  const int kt = blockIdx.x & 15;
  const int k0 = kt * 64;
  const float* W = (m == 0) ? Wq : (m == 1) ? Wk : Wv;
  {
    const int r = threadIdx.x >> 2, c4 = threadIdx.x & 3;
    #pragma unroll
    for (int j = 0; j < 4; ++j) {
      const float4 f = *(const float4*)(W + (size_t)(k0 + r) * NH + c4 * 16 + j * 4);
      t[r][c4 * 16 + j * 4 + 0] = f.x;
      t[r][c4 * 16 + j * 4 + 1] = f.y;
      t[r][c4 * 16 + j * 4 + 2] = f.z;
      t[r][c4 * 16 + j * 4 + 3] = f.w;
    }
  }
  __syncthreads();
  const int n = threadIdx.x >> 2, kc = threadIdx.x & 3;
  u16x8 a, b;
  #pragma unroll
  for (int j = 0; j < 8; ++j) a[j] = f2b(t[kc * 16 + j][n]);
  #pragma unroll
  for (int j = 0; j < 8; ++j) b[j] = f2b(t[kc * 16 + 8 + j][n]);
  u16* dst = wt + ((size_t)(m * 64 + n)) * NC + k0 + kc * 16;
  *(u16x8*)dst = a;
  *(u16x8*)(dst + 8) = b;
}

// ---------------- proj-v3: grid (512 M-chunks, 3 matrices), 256 thr, 4 waves.
// Per block: 16 rows x 64 cols of ONE matrix. LDS 24KB -> 6 blocks/CU. (r15 best)
__global__ __launch_bounds__(256) void proj_kernel(const float* __restrict__ x,
                                                   const u16* __restrict__ wt,
                                                   u16* __restrict__ qo,
                                                   u16* __restrict__ ko,
                                                   u16* __restrict__ vto) {
  __shared__ float fA[2][16 * 64];   // 4KB each
  __shared__ u16 sB[2][64 * 64];     // 8KB each
  const int tid = threadIdx.x;
  const int lane = tid & 63;
  const int w = tid >> 6;            // colfrag 0..3
  const int g = lane >> 4;
  const int li = lane & 15;
  const int row0 = blockIdx.x * 16;
  const int m = blockIdx.y;          // 0=q 1=k 2=v
  const int wbase = tid & 0xC0;
  const u16* wslice = wt + (size_t)m * 64 * NC;

  const f32x4 zero = {0.f, 0.f, 0.f, 0.f};
  f32x4 acc = zero;

  const int ar = tid >> 4;           // A row 0..15
  const int ac = tid & 15;           // A 16B chunk 0..15
  const float* asrc0 = x + (size_t)(row0 + ar) * NC + ((ac ^ (ar & 7)) * 4);

  auto stage = [&](int kt, int nxt) {
    const int k0 = kt * 64;
    gl16(asrc0 + k0, (char*)fA[nxt] + wbase * 16);
    #pragma unroll
    for (int j = 0; j < 2; ++j) {
      const int cid = j * 256 + tid;
      const int n = cid >> 3, c = cid & 7;
      gl16(wslice + (size_t)n * NC + k0 + ((c ^ (n & 7)) * 8),
           (char*)sB[nxt] + (j * 4096 + wbase * 16));
    }
  };

  stage(0, 0);
  __syncthreads();

  for (int kt = 0; kt < 16; ++kt) {
    const int cur = kt & 1;
    if (kt < 15) stage(kt + 1, cur ^ 1);
    #pragma unroll
    for (int ks = 0; ks < 2; ++ks) {
      const int c0 = ks * 8 + g * 2;
      const f32x4 a0 = *(const f32x4*)&fA[cur][li * 64 + ((c0 ^ (li & 7)) * 4)];
      const f32x4 a1 = *(const f32x4*)&fA[cur][li * 64 + (((c0 + 1) ^ (li & 7)) * 4)];
      bf16x8 a;
      a[0]=(bf16_t)a0.x; a[1]=(bf16_t)a0.y; a[2]=(bf16_t)a0.z; a[3]=(bf16_t)a0.w;
      a[4]=(bf16_t)a1.x; a[5]=(bf16_t)a1.y; a[6]=(bf16_t)a1.z; a[7]=(bf16_t)a1.w;
      const int n = w * 16 + li;
      const bf16x8 b = *(const bf16x8*)&sB[cur][n * 64 + (((ks * 4 + g) ^ (n & 7)) * 8)];
      acc = __builtin_amdgcn_mfma_f32_16x16x32_bf16(a, b, acc, 0, 0, 0);
    }
    __syncthreads();
  }

  // epilogue: C/D layout col=lane&15, row=(lane>>4)*4+reg
  const int rr0 = row0 + g * 4;
  if (m == 0) {
    #pragma unroll
    for (int i = 0; i < 4; ++i)
      qo[(size_t)(rr0 + i) * NH + w * 16 + li] = f2b(acc[i]);
  } else if (m == 1) {
    #pragma unroll
    for (int i = 0; i < 4; ++i)
      ko[(size_t)(rr0 + i) * NH + w * 16 + li] = f2b(acc[i]);
  } else {
    u16x4 pv;
    #pragma unroll
    for (int i = 0; i < 4; ++i) pv[i] = f2b(acc[i]);
    const int hs = w * 16 + li;
    const int bidx = rr0 >> 11;
    const int tt = rr0 & 2047;
    const int tile = tt >> 6, off = tt & 63;
    *(u16x4*)&vto[(((size_t)(bidx * 32 + tile) * 64) + hs) * 64 + off] = pv;
  }
}

// ---------------- attention (r13): pair (j, 127-j) of 16-row q-tiles => 65 kv-tiles
// per block; 8 waves = 8 kv-splits, wave-private gl16 K/V dbuf, counted vmcnt,
// static softmax, in-block exact merge.
struct AttnGrp {
  union {
    struct { u16 K[2][32 * 64]; u16 V[2][64 * 32]; } st;  // 16 KB
    struct { float mo[2][16][64]; float ml[2][16]; } mg;  // merge alias
  } u;
};

__global__ __launch_bounds__(512) void attn_kernel(const u16* __restrict__ qg,
                                                   const u16* __restrict__ kg,
                                                   const u16* __restrict__ vtg,
                                                   float* __restrict__ out) {
  __shared__ AttnGrp grp[8];
  __shared__ u16 sP[8][16 * 32];
  const int tid = threadIdx.x;
  const int lane = tid & 63;
  const int s = tid >> 6;
  const int g = lane >> 4;
  const int li = lane & 15;
  const int jA = blockIdx.x & 63;
  const int bb = blockIdx.x >> 6;
  const int jB = 127 - jA;
  const size_t bt0 = (size_t)bb * NT;
  const int q0A = jA * 16, q0B = jB * 16;
  const int n1 = (jA >> 1) + 1;
  const int nB = 64 - (jA >> 1);
  (void)nB;

  bf16x8 aqA[2], aqB[2];
  #pragma unroll
  for (int ks = 0; ks < 2; ++ks) {
    aqA[ks] = *(const bf16x8*)(qg + (bt0 + q0A + li) * NH + ks * 32 + g * 8);
    aqB[ks] = *(const bf16x8*)(qg + (bt0 + q0B + li) * NH + ks * 32 + g * 8);
  }

  const f32x4 zero = {0.f, 0.f, 0.f, 0.f};
  f32x4 oA[4], oB[4];
  float lA[4], lB[4];
  #pragma unroll
  for (int i = 0; i < 4; ++i) { oA[i] = zero; oB[i] = zero; lA[i] = 0.f; lB[i] = 0.f; }

  auto stageKV = [&](int v, int b) {
    const int kvt = (v < n1) ? v : v - n1;
    const size_t kbase = bt0 + (size_t)kvt * 32;
    #pragma unroll
    for (int jj = 0; jj < 4; ++jj) {
      const int idx = jj * 64 + lane;
      const int n = idx >> 3, c = idx & 7;
      gl16(kg + (kbase + n) * NH + ((c ^ (n & 7)) * 8),
           (char*)grp[s].u.st.K[b] + jj * 1024);
    }
    const size_t vbase = ((size_t)(bb * 32 + (kvt >> 1))) * 64;
    const int hoff = (kvt & 1) * 32;
    #pragma unroll
    for (int jj = 0; jj < 4; ++jj) {
      const int idx = jj * 64 + lane;
      const int n = idx >> 2, c = idx & 3;
      gl16(vtg + (vbase + n) * 64 + hoff + ((c ^ (n & 3) ^ ((n >> 2) & 3)) * 8),
           (char*)grp[s].u.st.V[b] + jj * 1024);
    }
  };

  auto computeT = [&](const bf16x8 (&aq)[2], f32x4 (&o)[4], float (&ls)[4],
                      int q0, int kv0, int b) {
    f32x4 sc2[2] = {zero, zero};
    #pragma unroll
    for (int ks = 0; ks < 2; ++ks) {
      #pragma unroll
      for (int fn = 0; fn < 2; ++fn) {
        const int n = fn * 16 + li;
        const bf16x8 bk = *(const bf16x8*)&grp[s].u.st.K[b][n * 64 + (((ks * 4 + g) ^ (n & 7)) * 8)];
        sc2[fn] = __builtin_amdgcn_mfma_f32_16x16x32_bf16(aq[ks], bk, sc2[fn], 0, 0, 0);
      }
    }
    const bool needmask = (kv0 + 31 > q0);
    #pragma unroll
    for (int fn = 0; fn < 2; ++fn) {
      #pragma unroll
      for (int i = 0; i < 4; ++i) {
        const int q = g * 4 + i;
        float v = sc2[fn][i] * 0.125f;
        if (needmask && (kv0 + fn * 16 + li > q0 + q)) v = -1e30f;
        const float e = __expf(v);
        ls[i] += e;
        const int kc = fn * 2 + (li >> 3);
        sP[s][q * 32 + ((kc ^ (q & 3) ^ ((q >> 2) & 3)) * 8) + (li & 7)] = f2b(e);
      }
    }
    const bf16x8 pa = *(const bf16x8*)&sP[s][li * 32 + ((g ^ (li & 3) ^ ((li >> 2) & 3)) * 8)];
    #pragma unroll
    for (int fn = 0; fn < 4; ++fn) {
      const int n = fn * 16 + li;
      const bf16x8 bv = *(const bf16x8*)&grp[s].u.st.V[b][n * 32 + ((g ^ (n & 3) ^ ((n >> 2) & 3)) * 8)];
      o[fn] = __builtin_amdgcn_mfma_f32_16x16x32_bf16(pa, bv, o[fn], 0, 0, 0);
    }
  };

  const int nt = (64 - s) / 8 + 1;    // 65 tiles: split s gets 8 or 9
  int v = s;
  stageKV(v, 0);
  for (int k = 0; k < nt; ++k) {
    if (k + 1 < nt) {
      stageKV(v + 8, (k + 1) & 1);
      asm volatile("s_waitcnt vmcnt(8)" ::: "memory");
    } else {
      asm volatile("s_waitcnt vmcnt(0)" ::: "memory");
    }
    const int b = k & 1;
    if (v < n1) computeT(aqA, oA, lA, q0A, v * 32, b);
    else        computeT(aqB, oB, lB, q0B, (v - n1) * 32, b);
    v += 8;
  }

  #pragma unroll
  for (int i = 0; i < 4; ++i) {
    float a = lA[i], c = lB[i];
    a += __shfl_xor(a, 1); c += __shfl_xor(c, 1);
    a += __shfl_xor(a, 2); c += __shfl_xor(c, 2);
    a += __shfl_xor(a, 4); c += __shfl_xor(c, 4);
    a += __shfl_xor(a, 8); c += __shfl_xor(c, 8);
    lA[i] = a; lB[i] = c;
  }

  #pragma unroll
  for (int fn = 0; fn < 4; ++fn) {
    #pragma unroll
    for (int i = 0; i < 4; ++i) {
      grp[s].u.mg.mo[0][g * 4 + i][fn * 16 + li] = oA[fn][i];
      grp[s].u.mg.mo[1][g * 4 + i][fn * 16 + li] = oB[fn][i];
    }
  }
  if (li == 0) {
    #pragma unroll
    for (int i = 0; i < 4; ++i) {
      grp[s].u.mg.ml[0][g * 4 + i] = lA[i];
      grp[s].u.mg.ml[1][g * 4 + i] = lB[i];
    }
  }
  __syncthreads();

  {
    const int base = tid * 4;
    const int tile = base >> 10;
    const int r = (base >> 6) & 15;
    const int c0 = base & 63;
    float L = 0.f;
    f32x4 acc = zero;
    #pragma unroll
    for (int s8 = 0; s8 < 8; ++s8) {
      L += grp[s8].u.mg.ml[tile][r];
      acc += *(const f32x4*)&grp[s8].u.mg.mo[tile][r][c0];
    }
    const int row = (tile ? q0B : q0A) + r;
    const float inv = 1.f / L;
    acc *= inv;
    *(f32x4*)&out[(bt0 + row) * NH + c0] = acc;
  }
}

extern "C" void kernel_launch(void* const* d_in, const int* in_sizes, int n_in,
                              void* d_out, int out_size, void* d_ws, size_t ws_size,
                              hipStream_t stream) {
  (void)in_sizes; (void)n_in; (void)out_size; (void)ws_size;
  const float* x  = (const float*)d_in[0];
  const float* Wq = (const float*)d_in[1];
  const float* Wk = (const float*)d_in[2];
  const float* Wv = (const float*)d_in[3];
  float* out = (float*)d_out;
  char* ws = (char*)d_ws;
  u16* qb  = (u16*)(ws);                    // 1 MB   : q bf16 [8192][64]
  u16* kb  = (u16*)(ws + (1u << 20));       // 1 MB   : k bf16 [8192][64]
  u16* vtb = (u16*)(ws + (2u << 20));       // 1 MB   : v^T bf16 tiled [4][32][64][64]
  u16* wtb = (u16*)(ws + (3u << 20));       // 384 KB : WT bf16 [3][64][1024]
  hipLaunchKernelGGL(wt_kernel,   dim3(48),     dim3(256), 0, stream, Wq, Wk, Wv, wtb);
  hipLaunchKernelGGL(proj_kernel, dim3(512, 3), dim3(256), 0, stream, x, wtb, qb, kb, vtb);
  hipLaunchKernelGGL(attn_kernel, dim3(256),    dim3(512), 0, stream, qb, kb, vtb, out);
}

// Round 23
// 36.675 us; speedup vs baseline: 1.2029x; 1.0339x over previous
//
#include <hip/hip_runtime.h>
#include <stdint.h>

#define NB 4
#define NT 2048
#define NC 1024
#define NH 64
#define NM (NB*NT)

typedef unsigned short u16;
typedef unsigned int u32;
typedef __bf16 bf16_t;
typedef float f32x4 __attribute__((ext_vector_type(4)));
typedef bf16_t bf16x8 __attribute__((ext_vector_type(8)));
typedef u16 u16x8 __attribute__((ext_vector_type(8)));
typedef u16 u16x4 __attribute__((ext_vector_type(4)));

__device__ __forceinline__ u16 f2b(float f) {
  return __builtin_bit_cast(u16, (bf16_t)f);
}

// async global->LDS 16B: LDS dest = WAVE-UNIFORM base + lane*16 (m104);
// per-lane swizzle folded into the GLOBAL source address (m173).
__device__ __forceinline__ void gl16(const void* g, void* l) {
  __builtin_amdgcn_global_load_lds(
      (const __attribute__((address_space(1))) u32*)g,
      (__attribute__((address_space(3))) u32*)l, 16, 0, 0);
}

// ---------------- Wq/Wk/Wv [1024][64] f32 -> WT [3][64][1024] bf16 (transposed)
__global__ __launch_bounds__(256) void wt_kernel(const float* __restrict__ Wq,
                                                 const float* __restrict__ Wk,
                                                 const float* __restrict__ Wv,
                                                 u16* __restrict__ wt) {
  __shared__ float t[64][65];
  const int m = blockIdx.x >> 4;
  const int kt = blockIdx.x & 15;
  const int k0 = kt * 64;
  const float* W = (m == 0) ? Wq : (m == 1) ? Wk : Wv;
  {
    const int r = threadIdx.x >> 2, c4 = threadIdx.x & 3;
    #pragma unroll
    for (int j = 0; j < 4; ++j) {
      const float4 f = *(const float4*)(W + (size_t)(k0 + r) * NH + c4 * 16 + j * 4);
      t[r][c4 * 16 + j * 4 + 0] = f.x;
      t[r][c4 * 16 + j * 4 + 1] = f.y;
      t[r][c4 * 16 + j * 4 + 2] = f.z;
      t[r][c4 * 16 + j * 4 + 3] = f.w;
    }
  }
  __syncthreads();
  const int n = threadIdx.x >> 2, kc = threadIdx.x & 3;
  u16x8 a, b;
  #pragma unroll
  for (int j = 0; j < 8; ++j) a[j] = f2b(t[kc * 16 + j][n]);
  #pragma unroll
  for (int j = 0; j < 8; ++j) b[j] = f2b(t[kc * 16 + 8 + j][n]);
  u16* dst = wt + ((size_t)(m * 64 + n)) * NC + k0 + kc * 16;
  *(u16x8*)dst = a;
  *(u16x8*)(dst + 8) = b;
}

// ---------------- proj-v9: r15 template with BM=32. grid (256,3) x 256 thr, 4 waves.
// Per block: 32 rows x 64 cols of ONE matrix; K-step 64, 16 steps, dbuf LDS 32KB
// -> 5 blocks/CU. Traffic 196MB (vs r15's 292MB) in near-identical delivery regime.
__global__ __launch_bounds__(256) void proj_kernel(const float* __restrict__ x,
                                                   const u16* __restrict__ wt,
                                                   u16* __restrict__ qo,
                                                   u16* __restrict__ ko,
                                                   u16* __restrict__ vto) {
  __shared__ float fA[2][32 * 64];   // 8KB each: [row][16B-chunk^(row&7)]
  __shared__ u16 sB[2][64 * 64];     // 8KB each: [n][16B-chunk^(n&7)]
  const int tid = threadIdx.x;
  const int lane = tid & 63;
  const int w = tid >> 6;            // colfrag 0..3
  const int g = lane >> 4;
  const int li = lane & 15;
  const int row0 = blockIdx.x * 32;
  const int m = blockIdx.y;          // 0=q 1=k 2=v
  const int wbase = tid & 0xC0;
  const u16* wslice = wt + (size_t)m * 64 * NC;

  const f32x4 zero = {0.f, 0.f, 0.f, 0.f};
  f32x4 acc[2];
  acc[0] = zero; acc[1] = zero;

  auto stage = [&](int kt, int nxt) {
    const int k0 = kt * 64;
    #pragma unroll
    for (int j = 0; j < 2; ++j) {    // A: 32 rows x 16 chunks = 512
      const int slot = j * 256 + tid;
      const int r = slot >> 4, c = slot & 15;
      gl16(x + (size_t)(row0 + r) * NC + k0 + ((c ^ (r & 7)) * 4),
           (char*)fA[nxt] + (j * 4096 + wbase * 16));
    }
    #pragma unroll
    for (int j = 0; j < 2; ++j) {    // B: 64 rows x 8 chunks = 512
      const int slot = j * 256 + tid;
      const int n = slot >> 3, c = slot & 7;
      gl16(wslice + (size_t)n * NC + k0 + ((c ^ (n & 7)) * 8),
           (char*)sB[nxt] + (j * 4096 + wbase * 16));
    }
  };

  stage(0, 0);
  __syncthreads();

  for (int kt = 0; kt < 16; ++kt) {
    const int cur = kt & 1;
    if (kt < 15) stage(kt + 1, cur ^ 1);
    #pragma unroll
    for (int ks = 0; ks < 2; ++ks) {
      const int n = w * 16 + li;
      const bf16x8 b = *(const bf16x8*)&sB[cur][n * 64 + (((ks * 4 + g) ^ (n & 7)) * 8)];
      #pragma unroll
      for (int rt = 0; rt < 2; ++rt) {
        const int r = rt * 16 + li;
        const int c0 = ks * 8 + g * 2;
        const f32x4 a0 = *(const f32x4*)&fA[cur][r * 64 + ((c0 ^ (r & 7)) * 4)];
        const f32x4 a1 = *(const f32x4*)&fA[cur][r * 64 + (((c0 + 1) ^ (r & 7)) * 4)];
        bf16x8 a;
        a[0]=(bf16_t)a0.x; a[1]=(bf16_t)a0.y; a[2]=(bf16_t)a0.z; a[3]=(bf16_t)a0.w;
        a[4]=(bf16_t)a1.x; a[5]=(bf16_t)a1.y; a[6]=(bf16_t)a1.z; a[7]=(bf16_t)a1.w;
        acc[rt] = __builtin_amdgcn_mfma_f32_16x16x32_bf16(a, b, acc[rt], 0, 0, 0);
      }
    }
    __syncthreads();
  }

  // epilogue: C/D layout col=lane&15, row=(lane>>4)*4+reg
  #pragma unroll
  for (int rt = 0; rt < 2; ++rt) {
    const int rr0 = row0 + rt * 16 + g * 4;
    if (m == 0) {
      #pragma unroll
      for (int i = 0; i < 4; ++i)
        qo[(size_t)(rr0 + i) * NH + w * 16 + li] = f2b(acc[rt][i]);
    } else if (m == 1) {
      #pragma unroll
      for (int i = 0; i < 4; ++i)
        ko[(size_t)(rr0 + i) * NH + w * 16 + li] = f2b(acc[rt][i]);
    } else {
      u16x4 pv;
      #pragma unroll
      for (int i = 0; i < 4; ++i) pv[i] = f2b(acc[rt][i]);
      const int hs = w * 16 + li;
      const int bidx = rr0 >> 11;
      const int tt = rr0 & 2047;
      const int tile = tt >> 6, off = tt & 63;
      *(u16x4*)&vto[(((size_t)(bidx * 32 + tile) * 64) + hs) * 64 + off] = pv;
    }
  }
}

// ---------------- attention (r13 — byte-identical)
struct AttnGrp {
  union {
    struct { u16 K[2][32 * 64]; u16 V[2][64 * 32]; } st;  // 16 KB
    struct { float mo[2][16][64]; float ml[2][16]; } mg;  // merge alias
  } u;
};

__global__ __launch_bounds__(512) void attn_kernel(const u16* __restrict__ qg,
                                                   const u16* __restrict__ kg,
                                                   const u16* __restrict__ vtg,
                                                   float* __restrict__ out) {
  __shared__ AttnGrp grp[8];
  __shared__ u16 sP[8][16 * 32];
  const int tid = threadIdx.x;
  const int lane = tid & 63;
  const int s = tid >> 6;
  const int g = lane >> 4;
  const int li = lane & 15;
  const int jA = blockIdx.x & 63;
  const int bb = blockIdx.x >> 6;
  const int jB = 127 - jA;
  const size_t bt0 = (size_t)bb * NT;
  const int q0A = jA * 16, q0B = jB * 16;
  const int n1 = (jA >> 1) + 1;

  bf16x8 aqA[2], aqB[2];
  #pragma unroll
  for (int ks = 0; ks < 2; ++ks) {
    aqA[ks] = *(const bf16x8*)(qg + (bt0 + q0A + li) * NH + ks * 32 + g * 8);
    aqB[ks] = *(const bf16x8*)(qg + (bt0 + q0B + li) * NH + ks * 32 + g * 8);
  }

  const f32x4 zero = {0.f, 0.f, 0.f, 0.f};
  f32x4 oA[4], oB[4];
  float lA[4], lB[4];
  #pragma unroll
  for (int i = 0; i < 4; ++i) { oA[i] = zero; oB[i] = zero; lA[i] = 0.f; lB[i] = 0.f; }

  auto stageKV = [&](int v, int b) {
    const int kvt = (v < n1) ? v : v - n1;
    const size_t kbase = bt0 + (size_t)kvt * 32;
    #pragma unroll
    for (int jj = 0; jj < 4; ++jj) {
      const int idx = jj * 64 + lane;
      const int n = idx >> 3, c = idx & 7;
      gl16(kg + (kbase + n) * NH + ((c ^ (n & 7)) * 8),
           (char*)grp[s].u.st.K[b] + jj * 1024);
    }
    const size_t vbase = ((size_t)(bb * 32 + (kvt >> 1))) * 64;
    const int hoff = (kvt & 1) * 32;
    #pragma unroll
    for (int jj = 0; jj < 4; ++jj) {
      const int idx = jj * 64 + lane;
      const int n = idx >> 2, c = idx & 3;
      gl16(vtg + (vbase + n) * 64 + hoff + ((c ^ (n & 3) ^ ((n >> 2) & 3)) * 8),
           (char*)grp[s].u.st.V[b] + jj * 1024);
    }
  };

  auto computeT = [&](const bf16x8 (&aq)[2], f32x4 (&o)[4], float (&ls)[4],
                      int q0, int kv0, int b) {
    f32x4 sc2[2] = {zero, zero};
    #pragma unroll
    for (int ks = 0; ks < 2; ++ks) {
      #pragma unroll
      for (int fn = 0; fn < 2; ++fn) {
        const int n = fn * 16 + li;
        const bf16x8 bk = *(const bf16x8*)&grp[s].u.st.K[b][n * 64 + (((ks * 4 + g) ^ (n & 7)) * 8)];
        sc2[fn] = __builtin_amdgcn_mfma_f32_16x16x32_bf16(aq[ks], bk, sc2[fn], 0, 0, 0);
      }
    }
    const bool needmask = (kv0 + 31 > q0);
    #pragma unroll
    for (int fn = 0; fn < 2; ++fn) {
      #pragma unroll
      for (int i = 0; i < 4; ++i) {
        const int q = g * 4 + i;
        float v = sc2[fn][i] * 0.125f;
        if (needmask && (kv0 + fn * 16 + li > q0 + q)) v = -1e30f;
        const float e = __expf(v);
        ls[i] += e;
        const int kc = fn * 2 + (li >> 3);
        sP[s][q * 32 + ((kc ^ (q & 3) ^ ((q >> 2) & 3)) * 8) + (li & 7)] = f2b(e);
      }
    }
    const bf16x8 pa = *(const bf16x8*)&sP[s][li * 32 + ((g ^ (li & 3) ^ ((li >> 2) & 3)) * 8)];
    #pragma unroll
    for (int fn = 0; fn < 4; ++fn) {
      const int n = fn * 16 + li;
      const bf16x8 bv = *(const bf16x8*)&grp[s].u.st.V[b][n * 32 + ((g ^ (n & 3) ^ ((n >> 2) & 3)) * 8)];
      o[fn] = __builtin_amdgcn_mfma_f32_16x16x32_bf16(pa, bv, o[fn], 0, 0, 0);
    }
  };

  const int nt = (64 - s) / 8 + 1;    // 65 tiles: split s gets 8 or 9
  int v = s;
  stageKV(v, 0);
  for (int k = 0; k < nt; ++k) {
    if (k + 1 < nt) {
      stageKV(v + 8, (k + 1) & 1);
      asm volatile("s_waitcnt vmcnt(8)" ::: "memory");
    } else {
      asm volatile("s_waitcnt vmcnt(0)" ::: "memory");
    }
    const int b = k & 1;
    if (v < n1) computeT(aqA, oA, lA, q0A, v * 32, b);
    else        computeT(aqB, oB, lB, q0B, (v - n1) * 32, b);
    v += 8;
  }

  #pragma unroll
  for (int i = 0; i < 4; ++i) {
    float a = lA[i], c = lB[i];
    a += __shfl_xor(a, 1); c += __shfl_xor(c, 1);
    a += __shfl_xor(a, 2); c += __shfl_xor(c, 2);
    a += __shfl_xor(a, 4); c += __shfl_xor(c, 4);
    a += __shfl_xor(a, 8); c += __shfl_xor(c, 8);
    lA[i] = a; lB[i] = c;
  }

  #pragma unroll
  for (int fn = 0; fn < 4; ++fn) {
    #pragma unroll
    for (int i = 0; i < 4; ++i) {
      grp[s].u.mg.mo[0][g * 4 + i][fn * 16 + li] = oA[fn][i];
      grp[s].u.mg.mo[1][g * 4 + i][fn * 16 + li] = oB[fn][i];
    }
  }
  if (li == 0) {
    #pragma unroll
    for (int i = 0; i < 4; ++i) {
      grp[s].u.mg.ml[0][g * 4 + i] = lA[i];
      grp[s].u.mg.ml[1][g * 4 + i] = lB[i];
    }
  }
  __syncthreads();

  {
    const int base = tid * 4;
    const int tile = base >> 10;
    const int r = (base >> 6) & 15;
    const int c0 = base & 63;
    float L = 0.f;
    f32x4 acc = zero;
    #pragma unroll
    for (int s8 = 0; s8 < 8; ++s8) {
      L += grp[s8].u.mg.ml[tile][r];
      acc += *(const f32x4*)&grp[s8].u.mg.mo[tile][r][c0];
    }
    const int row = (tile ? q0B : q0A) + r;
    const float inv = 1.f / L;
    acc *= inv;
    *(f32x4*)&out[(bt0 + row) * NH + c0] = acc;
  }
}

extern "C" void kernel_launch(void* const* d_in, const int* in_sizes, int n_in,
                              void* d_out, int out_size, void* d_ws, size_t ws_size,
                              hipStream_t stream) {
  (void)in_sizes; (void)n_in; (void)out_size; (void)ws_size;
  const float* x  = (const float*)d_in[0];
  const float* Wq = (const float*)d_in[1];
  const float* Wk = (const float*)d_in[2];
  const float* Wv = (const float*)d_in[3];
  float* out = (float*)d_out;
  char* ws = (char*)d_ws;
  u16* qb  = (u16*)(ws);                    // 1 MB   : q bf16 [8192][64]
  u16* kb  = (u16*)(ws + (1u << 20));       // 1 MB   : k bf16 [8192][64]
  u16* vtb = (u16*)(ws + (2u << 20));       // 1 MB   : v^T bf16 tiled [4][32][64][64]
  u16* wtb = (u16*)(ws + (3u << 20));       // 384 KB : WT bf16 [3][64][1024]
  hipLaunchKernelGGL(wt_kernel,   dim3(48),     dim3(256), 0, stream, Wq, Wk, Wv, wtb);
  hipLaunchKernelGGL(proj_kernel, dim3(256, 3), dim3(256), 0, stream, x, wtb, qb, kb, vtb);
  hipLaunchKernelGGL(attn_kernel, dim3(256),    dim3(512), 0, stream, qb, kb, vtb, out);
}

// Round 24
// 35.398 us; speedup vs baseline: 1.2464x; 1.0361x over previous
//
#include <hip/hip_runtime.h>
#include <stdint.h>

#define NB 4
#define NT 2048
#define NC 1024
#define NH 64
#define NM (NB*NT)

typedef unsigned short u16;
typedef unsigned int u32;
typedef __bf16 bf16_t;
typedef float f32x4 __attribute__((ext_vector_type(4)));
typedef bf16_t bf16x8 __attribute__((ext_vector_type(8)));
typedef u16 u16x8 __attribute__((ext_vector_type(8)));
typedef u16 u16x4 __attribute__((ext_vector_type(4)));

__device__ __forceinline__ u16 f2b(float f) {
  return __builtin_bit_cast(u16, (bf16_t)f);
}

// async global->LDS 16B: LDS dest = WAVE-UNIFORM base + lane*16 (m104);
// per-lane swizzle folded into the GLOBAL source address (m173).
__device__ __forceinline__ void gl16(const void* g, void* l) {
  __builtin_amdgcn_global_load_lds(
      (const __attribute__((address_space(1))) u32*)g,
      (__attribute__((address_space(3))) u32*)l, 16, 0, 0);
}

// ---------------- Wq/Wk/Wv [1024][64] f32 -> WT [3][64][1024] bf16 (transposed)
__global__ __launch_bounds__(256) void wt_kernel(const float* __restrict__ Wq,
                                                 const float* __restrict__ Wk,
                                                 const float* __restrict__ Wv,
                                                 u16* __restrict__ wt) {
  __shared__ float t[64][65];
  const int m = blockIdx.x >> 4;
  const int kt = blockIdx.x & 15;
  const int k0 = kt * 64;
  const float* W = (m == 0) ? Wq : (m == 1) ? Wk : Wv;
  {
    const int r = threadIdx.x >> 2, c4 = threadIdx.x & 3;
    #pragma unroll
    for (int j = 0; j < 4; ++j) {
      const float4 f = *(const float4*)(W + (size_t)(k0 + r) * NH + c4 * 16 + j * 4);
      t[r][c4 * 16 + j * 4 + 0] = f.x;
      t[r][c4 * 16 + j * 4 + 1] = f.y;
      t[r][c4 * 16 + j * 4 + 2] = f.z;
      t[r][c4 * 16 + j * 4 + 3] = f.w;
    }
  }
  __syncthreads();
  const int n = threadIdx.x >> 2, kc = threadIdx.x & 3;
  u16x8 a, b;
  #pragma unroll
  for (int j = 0; j < 8; ++j) a[j] = f2b(t[kc * 16 + j][n]);
  #pragma unroll
  for (int j = 0; j < 8; ++j) b[j] = f2b(t[kc * 16 + 8 + j][n]);
  u16* dst = wt + ((size_t)(m * 64 + n)) * NC + k0 + kc * 16;
  *(u16x8*)dst = a;
  *(u16x8*)(dst + 8) = b;
}

// ---------------- proj-v10: v9 with 512 threads (8 waves = 2 row-sub x 4 colfrag).
// Same 32KB LDS, same traffic (196MB), same swizzles/math — occupancy becomes
// thread-capped: 4 blocks/CU x 8 waves = 32 waves/CU (vs v9's 20).
__global__ __launch_bounds__(512) void proj_kernel(const float* __restrict__ x,
                                                   const u16* __restrict__ wt,
                                                   u16* __restrict__ qo,
                                                   u16* __restrict__ ko,
                                                   u16* __restrict__ vto) {
  __shared__ float fA[2][32 * 64];   // 8KB each: [row][16B-chunk^(row&7)]
  __shared__ u16 sB[2][64 * 64];     // 8KB each: [n][16B-chunk^(n&7)]
  const int tid = threadIdx.x;       // 0..511
  const int lane = tid & 63;
  const int wv = tid >> 6;           // 0..7
  const int rt = wv & 1;             // row subtile
  const int w = wv >> 1;             // colfrag 0..3
  const int g = lane >> 4;
  const int li = lane & 15;
  const int row0 = blockIdx.x * 32;
  const int m = blockIdx.y;          // 0=q 1=k 2=v
  const int wbase16 = (tid & 0x1C0) * 16;   // wave-uniform LDS byte base
  const u16* wslice = wt + (size_t)m * 64 * NC;

  const f32x4 zero = {0.f, 0.f, 0.f, 0.f};
  f32x4 acc = zero;

  // staging coords: 1 gl16 each for A (32r x 16ch) and B (64n x 8ch) per thread
  const int ar = tid >> 4, ac = tid & 15;
  const int bn = tid >> 3, bc = tid & 7;
  const float* asrc = x + (size_t)(row0 + ar) * NC + ((ac ^ (ar & 7)) * 4);
  const u16* bsrc = wslice + (size_t)bn * NC + ((bc ^ (bn & 7)) * 8);

  auto stage = [&](int kt, int nxt) {
    const int k0 = kt * 64;
    gl16(asrc + k0, (char*)fA[nxt] + wbase16 + (lane << 4));
    gl16(bsrc + k0, (char*)sB[nxt] + wbase16 + (lane << 4));
  };

  stage(0, 0);
  __syncthreads();

  for (int kt = 0; kt < 16; ++kt) {
    const int cur = kt & 1;
    if (kt < 15) stage(kt + 1, cur ^ 1);
    #pragma unroll
    for (int ks = 0; ks < 2; ++ks) {
      const int n = w * 16 + li;
      const bf16x8 b = *(const bf16x8*)&sB[cur][n * 64 + (((ks * 4 + g) ^ (n & 7)) * 8)];
      const int r = rt * 16 + li;
      const int c0 = ks * 8 + g * 2;
      const f32x4 a0 = *(const f32x4*)&fA[cur][r * 64 + ((c0 ^ (r & 7)) * 4)];
      const f32x4 a1 = *(const f32x4*)&fA[cur][r * 64 + (((c0 + 1) ^ (r & 7)) * 4)];
      bf16x8 a;
      a[0]=(bf16_t)a0.x; a[1]=(bf16_t)a0.y; a[2]=(bf16_t)a0.z; a[3]=(bf16_t)a0.w;
      a[4]=(bf16_t)a1.x; a[5]=(bf16_t)a1.y; a[6]=(bf16_t)a1.z; a[7]=(bf16_t)a1.w;
      acc = __builtin_amdgcn_mfma_f32_16x16x32_bf16(a, b, acc, 0, 0, 0);
    }
    __syncthreads();
  }

  // epilogue: C/D layout col=lane&15, row=(lane>>4)*4+reg
  const int rr0 = row0 + rt * 16 + g * 4;
  if (m == 0) {
    #pragma unroll
    for (int i = 0; i < 4; ++i)
      qo[(size_t)(rr0 + i) * NH + w * 16 + li] = f2b(acc[i]);
  } else if (m == 1) {
    #pragma unroll
    for (int i = 0; i < 4; ++i)
      ko[(size_t)(rr0 + i) * NH + w * 16 + li] = f2b(acc[i]);
  } else {
    u16x4 pv;
    #pragma unroll
    for (int i = 0; i < 4; ++i) pv[i] = f2b(acc[i]);
    const int hs = w * 16 + li;
    const int bidx = rr0 >> 11;
    const int tt = rr0 & 2047;
    const int tile = tt >> 6, off = tt & 63;
    *(u16x4*)&vto[(((size_t)(bidx * 32 + tile) * 64) + hs) * 64 + off] = pv;
  }
}

// ---------------- attention (r13 — byte-identical)
struct AttnGrp {
  union {
    struct { u16 K[2][32 * 64]; u16 V[2][64 * 32]; } st;  // 16 KB
    struct { float mo[2][16][64]; float ml[2][16]; } mg;  // merge alias
  } u;
};

__global__ __launch_bounds__(512) void attn_kernel(const u16* __restrict__ qg,
                                                   const u16* __restrict__ kg,
                                                   const u16* __restrict__ vtg,
                                                   float* __restrict__ out) {
  __shared__ AttnGrp grp[8];
  __shared__ u16 sP[8][16 * 32];
  const int tid = threadIdx.x;
  const int lane = tid & 63;
  const int s = tid >> 6;
  const int g = lane >> 4;
  const int li = lane & 15;
  const int jA = blockIdx.x & 63;
  const int bb = blockIdx.x >> 6;
  const int jB = 127 - jA;
  const size_t bt0 = (size_t)bb * NT;
  const int q0A = jA * 16, q0B = jB * 16;
  const int n1 = (jA >> 1) + 1;

  bf16x8 aqA[2], aqB[2];
  #pragma unroll
  for (int ks = 0; ks < 2; ++ks) {
    aqA[ks] = *(const bf16x8*)(qg + (bt0 + q0A + li) * NH + ks * 32 + g * 8);
    aqB[ks] = *(const bf16x8*)(qg + (bt0 + q0B + li) * NH + ks * 32 + g * 8);
  }

  const f32x4 zero = {0.f, 0.f, 0.f, 0.f};
  f32x4 oA[4], oB[4];
  float lA[4], lB[4];
  #pragma unroll
  for (int i = 0; i < 4; ++i) { oA[i] = zero; oB[i] = zero; lA[i] = 0.f; lB[i] = 0.f; }

  auto stageKV = [&](int v, int b) {
    const int kvt = (v < n1) ? v : v - n1;
    const size_t kbase = bt0 + (size_t)kvt * 32;
    #pragma unroll
    for (int jj = 0; jj < 4; ++jj) {
      const int idx = jj * 64 + lane;
      const int n = idx >> 3, c = idx & 7;
      gl16(kg + (kbase + n) * NH + ((c ^ (n & 7)) * 8),
           (char*)grp[s].u.st.K[b] + jj * 1024);
    }
    const size_t vbase = ((size_t)(bb * 32 + (kvt >> 1))) * 64;
    const int hoff = (kvt & 1) * 32;
    #pragma unroll
    for (int jj = 0; jj < 4; ++jj) {
      const int idx = jj * 64 + lane;
      const int n = idx >> 2, c = idx & 3;
      gl16(vtg + (vbase + n) * 64 + hoff + ((c ^ (n & 3) ^ ((n >> 2) & 3)) * 8),
           (char*)grp[s].u.st.V[b] + jj * 1024);
    }
  };

  auto computeT = [&](const bf16x8 (&aq)[2], f32x4 (&o)[4], float (&ls)[4],
                      int q0, int kv0, int b) {
    f32x4 sc2[2] = {zero, zero};
    #pragma unroll
    for (int ks = 0; ks < 2; ++ks) {
      #pragma unroll
      for (int fn = 0; fn < 2; ++fn) {
        const int n = fn * 16 + li;
        const bf16x8 bk = *(const bf16x8*)&grp[s].u.st.K[b][n * 64 + (((ks * 4 + g) ^ (n & 7)) * 8)];
        sc2[fn] = __builtin_amdgcn_mfma_f32_16x16x32_bf16(aq[ks], bk, sc2[fn], 0, 0, 0);
      }
    }
    const bool needmask = (kv0 + 31 > q0);
    #pragma unroll
    for (int fn = 0; fn < 2; ++fn) {
      #pragma unroll
      for (int i = 0; i < 4; ++i) {
        const int q = g * 4 + i;
        float v = sc2[fn][i] * 0.125f;
        if (needmask && (kv0 + fn * 16 + li > q0 + q)) v = -1e30f;
        const float e = __expf(v);
        ls[i] += e;
        const int kc = fn * 2 + (li >> 3);
        sP[s][q * 32 + ((kc ^ (q & 3) ^ ((q >> 2) & 3)) * 8) + (li & 7)] = f2b(e);
      }
    }
    const bf16x8 pa = *(const bf16x8*)&sP[s][li * 32 + ((g ^ (li & 3) ^ ((li >> 2) & 3)) * 8)];
    #pragma unroll
    for (int fn = 0; fn < 4; ++fn) {
      const int n = fn * 16 + li;
      const bf16x8 bv = *(const bf16x8*)&grp[s].u.st.V[b][n * 32 + ((g ^ (n & 3) ^ ((n >> 2) & 3)) * 8)];
      o[fn] = __builtin_amdgcn_mfma_f32_16x16x32_bf16(pa, bv, o[fn], 0, 0, 0);
    }
  };

  const int nt = (64 - s) / 8 + 1;    // 65 tiles: split s gets 8 or 9
  int v = s;
  stageKV(v, 0);
  for (int k = 0; k < nt; ++k) {
    if (k + 1 < nt) {
      stageKV(v + 8, (k + 1) & 1);
      asm volatile("s_waitcnt vmcnt(8)" ::: "memory");
    } else {
      asm volatile("s_waitcnt vmcnt(0)" ::: "memory");
    }
    const int b = k & 1;
    if (v < n1) computeT(aqA, oA, lA, q0A, v * 32, b);
    else        computeT(aqB, oB, lB, q0B, (v - n1) * 32, b);
    v += 8;
  }

  #pragma unroll
  for (int i = 0; i < 4; ++i) {
    float a = lA[i], c = lB[i];
    a += __shfl_xor(a, 1); c += __shfl_xor(c, 1);
    a += __shfl_xor(a, 2); c += __shfl_xor(c, 2);
    a += __shfl_xor(a, 4); c += __shfl_xor(c, 4);
    a += __shfl_xor(a, 8); c += __shfl_xor(c, 8);
    lA[i] = a; lB[i] = c;
  }

  #pragma unroll
  for (int fn = 0; fn < 4; ++fn) {
    #pragma unroll
    for (int i = 0; i < 4; ++i) {
      grp[s].u.mg.mo[0][g * 4 + i][fn * 16 + li] = oA[fn][i];
      grp[s].u.mg.mo[1][g * 4 + i][fn * 16 + li] = oB[fn][i];
    }
  }
  if (li == 0) {
    #pragma unroll
    for (int i = 0; i < 4; ++i) {
      grp[s].u.mg.ml[0][g * 4 + i] = lA[i];
      grp[s].u.mg.ml[1][g * 4 + i] = lB[i];
    }
  }
  __syncthreads();

  {
    const int base = tid * 4;
    const int tile = base >> 10;
    const int r = (base >> 6) & 15;
    const int c0 = base & 63;
    float L = 0.f;
    f32x4 acc = zero;
    #pragma unroll
    for (int s8 = 0; s8 < 8; ++s8) {
      L += grp[s8].u.mg.ml[tile][r];
      acc += *(const f32x4*)&grp[s8].u.mg.mo[tile][r][c0];
    }
    const int row = (tile ? q0B : q0A) + r;
    const float inv = 1.f / L;
    acc *= inv;
    *(f32x4*)&out[(bt0 + row) * NH + c0] = acc;
  }
}

extern "C" void kernel_launch(void* const* d_in, const int* in_sizes, int n_in,
                              void* d_out, int out_size, void* d_ws, size_t ws_size,
                              hipStream_t stream) {
  (void)in_sizes; (void)n_in; (void)out_size; (void)ws_size;
  const float* x  = (const float*)d_in[0];
  const float* Wq = (const float*)d_in[1];
  const float* Wk = (const float*)d_in[2];
  const float* Wv = (const float*)d_in[3];
  float* out = (float*)d_out;
  char* ws = (char*)d_ws;
  u16* qb  = (u16*)(ws);                    // 1 MB   : q bf16 [8192][64]
  u16* kb  = (u16*)(ws + (1u << 20));       // 1 MB   : k bf16 [8192][64]
  u16* vtb = (u16*)(ws + (2u << 20));       // 1 MB   : v^T bf16 tiled [4][32][64][64]
  u16* wtb = (u16*)(ws + (3u << 20));       // 384 KB : WT bf16 [3][64][1024]
  hipLaunchKernelGGL(wt_kernel,   dim3(48),     dim3(256), 0, stream, Wq, Wk, Wv, wtb);
  hipLaunchKernelGGL(proj_kernel, dim3(256, 3), dim3(512), 0, stream, x, wtb, qb, kb, vtb);
  hipLaunchKernelGGL(attn_kernel, dim3(256),    dim3(512), 0, stream, qb, kb, vtb, out);
}